// Round 1
// baseline (123.964 us; speedup 1.0000x reference)
//
#include <hip/hip_runtime.h>

#define MARGIN 0.0625f

// Problem sizes (fixed by the reference)
#define P 4096        // 64*64 query points
#define M 100000      // means
#define G 500         // mean-chunks: 500*200 = 100000 exactly
#define CHUNK 200     // means per block
#define NQUAD (CHUNK / 4)   // 50 float4 groups per LDS array
#define QS 2          // query slabs (grid = G*QS = 1000 blocks)
#define R 8           // queries per thread (256*R*QS = 4096)

typedef float float2v __attribute__((ext_vector_type(2)));
typedef float float4v __attribute__((ext_vector_type(4)));

// ws layout (bytes):
//   pmin[P] (uint, float-bits running min) @ 0   -- 16 KB, L2-resident
#define WS_PMIN_OFF 0

// ---------------------------------------------------------------------------
// Kernel 1 (fused): per-block mean transform -> LDS, query transform,
// 200-mean scan, then filtered atomicMin(float-as-uint) into pmin[P].
// The old prep / partial / reduce1 stages are gone: cross-block min combine
// happens via atomics on a 16 KB buffer instead of an 8.4 MB matrix.
// All stored d2 values are fmax(...,0) >= +0.0, so uint order == float order.
// ---------------------------------------------------------------------------
__global__ __launch_bounds__(256, 4) void nn_kernel(
    const float* __restrict__ outputs,   // [P*3]
    const float* __restrict__ c2ws,      // [64*16]
    const float* __restrict__ scales,    // [64]
    const float* __restrict__ means,     // [M*3] raw
    unsigned int* __restrict__ pmin)     // [P] float-bits, init 0xFFFFFFFF
{
    const int t  = threadIdx.x;
    const int g  = blockIdx.x;
    const int qs = blockIdx.y;
    const int pbase = qs * (P / QS);
    const int mbase = g * CHUNK;

    // SoA chunk in LDS as float4 groups -> ds_read_b128, wave-uniform
    // addresses (broadcast, conflict-free).
    __shared__ float4v lxs[NQUAD], lys[NQUAD], lzs[NQUAD], lms[NQUAD];

    // ---- fused prep: transform this block's 200 raw means into LDS ----
    if (t < CHUNK) {
        const float* mp = means + 3 * (mbase + t);
        float x = mp[0], y = mp[1], z = mp[2];
        ((float*)lxs)[t] = -2.0f * x;
        ((float*)lys)[t] = -2.0f * y;
        ((float*)lzs)[t] = -2.0f * z;
        ((float*)lms)[t] = fmaf(x, x, fmaf(y, y, z * z));
    }

    // ---- queries: compute inline, splat to VGPR pairs once ----
    float2v qxs[R], qys[R], qzs[R], mn[R];
    float qq[R];
#pragma unroll
    for (int i = 0; i < R; ++i) {
        int p = pbase + i * 256 + t;
        int b = p >> 6;
        float s  = scales[b];
        float o0 = outputs[3 * p + 0];
        float o1 = outputs[3 * p + 1];
        float o2 = outputs[3 * p + 2];
        const float* cw = c2ws + b * 16;
        float q0 = fmaf(s, fmaf(cw[0],  o0, fmaf(cw[1],  o1, cw[2]  * o2)), cw[3]);
        float q1 = fmaf(s, fmaf(cw[4],  o0, fmaf(cw[5],  o1, cw[6]  * o2)), cw[7]);
        float q2 = fmaf(s, fmaf(cw[8],  o0, fmaf(cw[9],  o1, cw[10] * o2)), cw[11]);
        qq[i]  = fmaf(q0, q0, fmaf(q1, q1, q2 * q2));
        qxs[i] = (float2v){q0, q0};
        qys[i] = (float2v){q1, q1};
        qzs[i] = (float2v){q2, q2};
        mn[i]  = (float2v){1e30f, 1e30f};
    }

    __syncthreads();

    // ---- scan 50 mean-quads (2 pairs each) from LDS ----
#pragma unroll 2
    for (int j = 0; j < NQUAD; ++j) {
        float4v cx4 = lxs[j];   // wave-uniform address -> LDS broadcast
        float4v cy4 = lys[j];
        float4v cz4 = lzs[j];
        float4v cm4 = lms[j];
        float2v cx0 = __builtin_shufflevector(cx4, cx4, 0, 1);
        float2v cx1 = __builtin_shufflevector(cx4, cx4, 2, 3);
        float2v cy0 = __builtin_shufflevector(cy4, cy4, 0, 1);
        float2v cy1 = __builtin_shufflevector(cy4, cy4, 2, 3);
        float2v cz0 = __builtin_shufflevector(cz4, cz4, 0, 1);
        float2v cz1 = __builtin_shufflevector(cz4, cz4, 2, 3);
        float2v cm0 = __builtin_shufflevector(cm4, cm4, 0, 1);
        float2v cm1 = __builtin_shufflevector(cm4, cm4, 2, 3);
#pragma unroll
        for (int i = 0; i < R; ++i) {
            // d'(pair) = mm + (-2x)*qx + (-2y)*qy + (-2z)*qz
            float2v d0 = __builtin_elementwise_fma(qzs[i], cz0,
                         __builtin_elementwise_fma(qys[i], cy0,
                         __builtin_elementwise_fma(qxs[i], cx0, cm0)));
            float2v d1 = __builtin_elementwise_fma(qzs[i], cz1,
                         __builtin_elementwise_fma(qys[i], cy1,
                         __builtin_elementwise_fma(qxs[i], cx1, cm1)));
            mn[i] = __builtin_elementwise_min(mn[i], d0);
            mn[i] = __builtin_elementwise_min(mn[i], d1);
        }
    }

    // ---- epilogue: fold pair, add qq, clamp, filtered atomicMin ----
    // Filter read may be stale (only ever >= true current value, since pmin
    // decreases monotonically), so skipping is always safe; the atomic is
    // authoritative. Expected successful atomics ~= running minima ~ 30K
    // total, so same-line contention is negligible.
#pragma unroll
    for (int i = 0; i < R; ++i) {
        int p = pbase + i * 256 + t;
        float m = fminf(mn[i][0], mn[i][1]);
        float d = fmaxf(qq[i] + m, 0.0f);
        unsigned int bits = __float_as_uint(d);
        if (bits < pmin[p]) atomicMin(&pmin[p], bits);
    }
}

// ---------------------------------------------------------------------------
// Kernel 2: loss. pmin is 16 KB and L2-hot. relu(MARGIN-d)/P, wave-reduce,
// one atomicAdd per block (16 blocks).
// ---------------------------------------------------------------------------
__global__ __launch_bounds__(256) void finish_kernel(
    const unsigned int* __restrict__ pmin,
    float* __restrict__ out)
{
    const int t = threadIdx.x;
    const int q = blockIdx.x * 256 + t;

    float m = __uint_as_float(pmin[q]);
    float v = fmaxf(MARGIN - m, 0.0f) * (1.0f / (float)P);

#pragma unroll
    for (int off = 32; off > 0; off >>= 1)
        v += __shfl_down(v, off, 64);

    __shared__ float lds[4];
    int wid = t >> 6;
    if ((t & 63) == 0) lds[wid] = v;
    __syncthreads();
    if (t == 0)
        atomicAdd(out, lds[0] + lds[1] + lds[2] + lds[3]);
}

extern "C" void kernel_launch(void* const* d_in, const int* in_sizes, int n_in,
                              void* d_out, int out_size, void* d_ws, size_t ws_size,
                              hipStream_t stream) {
    const float* outputs = (const float*)d_in[0];  // (64,64,3)
    const float* c2ws    = (const float*)d_in[1];  // (64,4,4)
    const float* scales  = (const float*)d_in[2];  // (64,)
    const float* means   = (const float*)d_in[3];  // (100000,3)

    unsigned int* pmin = (unsigned int*)((char*)d_ws + WS_PMIN_OFF);
    float* out = (float*)d_out;

    // 0xFF bytes -> 0xFFFFFFFF = uint-max sentinel (beats any d2 bit pattern).
    hipMemsetAsync(pmin, 0xFF, P * sizeof(unsigned int), stream);
    hipMemsetAsync(out, 0, sizeof(float), stream);

    nn_kernel<<<dim3(G, QS), 256, 0, stream>>>(outputs, c2ws, scales, means, pmin);
    finish_kernel<<<P / 256, 256, 0, stream>>>(pmin, out);
}

// Round 2
// 103.998 us; speedup vs baseline: 1.1920x; 1.1920x over previous
//
#include <hip/hip_runtime.h>

#define MARGIN 0.0625f

// Problem sizes (fixed by the reference)
#define P 4096        // 64*64 query points
#define M 100000      // means
#define G 500         // mean-chunks: 500*200 = 100000 exactly
#define CHUNK 200     // means per block
#define NQUAD (CHUNK / 4)   // 50 float4 groups per LDS array
#define QS 2          // query slabs (grid = G*QS = 1000 blocks)
#define R 8           // queries per thread (256*R*QS = 4096)
#define NCOPY 16      // atomic spread: pmin[NCOPY][P]

typedef float float2v __attribute__((ext_vector_type(2)));
typedef float float4v __attribute__((ext_vector_type(4)));

// ws layout (bytes):
//   pmin[NCOPY][P] (uint, float-bits running min) @ 0  -- 256 KB, L2-resident
//   Spreading over 16 copies turns the 2M-atomic burst on 256 cache lines
//   (16 words/line -> ~8K serialized ops/line) into 4096 lines (~500/line).
#define WS_PMIN_OFF 0

// ---------------------------------------------------------------------------
// Kernel 1 (fused): per-block mean transform -> LDS, query transform,
// 200-mean scan (software-pipelined LDS quads), filtered atomicMin into
// pmin[g & 15][p]. All stored d2 are fmax(...,0) >= +0.0 so uint order ==
// float order.
// ---------------------------------------------------------------------------
__global__ __launch_bounds__(256, 4) void nn_kernel(
    const float* __restrict__ outputs,   // [P*3]
    const float* __restrict__ c2ws,      // [64*16]
    const float* __restrict__ scales,    // [64]
    const float* __restrict__ means,     // [M*3] raw
    unsigned int* __restrict__ pmin)     // [NCOPY*P] float-bits, init 0xFF..
{
    const int t  = threadIdx.x;
    const int g  = blockIdx.x;
    const int qs = blockIdx.y;
    const int pbase = qs * (P / QS);
    const int mbase = g * CHUNK;

    // SoA chunk in LDS as float4 groups -> ds_read_b128, wave-uniform
    // addresses (broadcast, conflict-free).
    __shared__ float4v lxs[NQUAD], lys[NQUAD], lzs[NQUAD], lms[NQUAD];

    // ---- fused prep: transform this block's 200 raw means into LDS ----
    if (t < CHUNK) {
        const float* mp = means + 3 * (mbase + t);
        float x = mp[0], y = mp[1], z = mp[2];
        ((float*)lxs)[t] = -2.0f * x;
        ((float*)lys)[t] = -2.0f * y;
        ((float*)lzs)[t] = -2.0f * z;
        ((float*)lms)[t] = fmaf(x, x, fmaf(y, y, z * z));
    }

    // ---- queries: compute inline, splat to VGPR pairs once ----
    float2v qxs[R], qys[R], qzs[R], mn[R];
    float qq[R];
#pragma unroll
    for (int i = 0; i < R; ++i) {
        int p = pbase + i * 256 + t;
        int b = p >> 6;
        float s  = scales[b];
        float o0 = outputs[3 * p + 0];
        float o1 = outputs[3 * p + 1];
        float o2 = outputs[3 * p + 2];
        const float* cw = c2ws + b * 16;
        float q0 = fmaf(s, fmaf(cw[0],  o0, fmaf(cw[1],  o1, cw[2]  * o2)), cw[3]);
        float q1 = fmaf(s, fmaf(cw[4],  o0, fmaf(cw[5],  o1, cw[6]  * o2)), cw[7]);
        float q2 = fmaf(s, fmaf(cw[8],  o0, fmaf(cw[9],  o1, cw[10] * o2)), cw[11]);
        qq[i]  = fmaf(q0, q0, fmaf(q1, q1, q2 * q2));
        qxs[i] = (float2v){q0, q0};
        qys[i] = (float2v){q1, q1};
        qzs[i] = (float2v){q2, q2};
        mn[i]  = (float2v){1e30f, 1e30f};
    }

    __syncthreads();

    // ---- scan 50 mean-quads, software-pipelined: next quad's ds_reads
    // are issued before this quad's 64 packed FMAs, so LDS latency hides
    // under compute instead of a bulk lgkmcnt(0) stall per unrolled body.
    float4v cx = lxs[0], cy = lys[0], cz = lzs[0], cm = lms[0];
#pragma unroll 2
    for (int j = 0; j < NQUAD; ++j) {
        int jn = (j + 1 < NQUAD) ? j + 1 : 0;   // uniform, scalar select
        float4v nx = lxs[jn], ny = lys[jn], nz = lzs[jn], nm = lms[jn];

        float2v cx0 = __builtin_shufflevector(cx, cx, 0, 1);
        float2v cx1 = __builtin_shufflevector(cx, cx, 2, 3);
        float2v cy0 = __builtin_shufflevector(cy, cy, 0, 1);
        float2v cy1 = __builtin_shufflevector(cy, cy, 2, 3);
        float2v cz0 = __builtin_shufflevector(cz, cz, 0, 1);
        float2v cz1 = __builtin_shufflevector(cz, cz, 2, 3);
        float2v cm0 = __builtin_shufflevector(cm, cm, 0, 1);
        float2v cm1 = __builtin_shufflevector(cm, cm, 2, 3);
#pragma unroll
        for (int i = 0; i < R; ++i) {
            // d'(pair) = mm + (-2x)*qx + (-2y)*qy + (-2z)*qz
            float2v d0 = __builtin_elementwise_fma(qzs[i], cz0,
                         __builtin_elementwise_fma(qys[i], cy0,
                         __builtin_elementwise_fma(qxs[i], cx0, cm0)));
            float2v d1 = __builtin_elementwise_fma(qzs[i], cz1,
                         __builtin_elementwise_fma(qys[i], cy1,
                         __builtin_elementwise_fma(qxs[i], cx1, cm1)));
            mn[i] = __builtin_elementwise_min(mn[i], d0);
            mn[i] = __builtin_elementwise_min(mn[i], d1);
        }
        cx = nx; cy = ny; cz = nz; cm = nm;
    }

    // ---- epilogue: fold pair, add qq, clamp, filtered atomicMin into
    // this block's spread copy. Filter read may be stale (monotonically
    // decreasing target), so skipping is always safe; atomic is
    // authoritative.
    unsigned int* __restrict__ pm = pmin + (g & (NCOPY - 1)) * P;
#pragma unroll
    for (int i = 0; i < R; ++i) {
        int p = pbase + i * 256 + t;
        float m = fminf(mn[i][0], mn[i][1]);
        float d = fmaxf(qq[i] + m, 0.0f);
        unsigned int bits = __float_as_uint(d);
        if (bits < pm[p]) atomicMin(&pm[p], bits);
    }
}

// ---------------------------------------------------------------------------
// Kernel 2: loss. Fold the 16 spread copies (256 KB, L2-hot), then
// relu(MARGIN-d)/P, wave-reduce, one atomicAdd per block (16 blocks).
// ---------------------------------------------------------------------------
__global__ __launch_bounds__(256) void finish_kernel(
    const unsigned int* __restrict__ pmin,
    float* __restrict__ out)
{
    const int t = threadIdx.x;
    const int q = blockIdx.x * 256 + t;

    unsigned int mb = 0xFFFFFFFFu;
#pragma unroll
    for (int c = 0; c < NCOPY; ++c)
        mb = min(mb, pmin[c * P + q]);

    float m = __uint_as_float(mb);
    float v = fmaxf(MARGIN - m, 0.0f) * (1.0f / (float)P);

#pragma unroll
    for (int off = 32; off > 0; off >>= 1)
        v += __shfl_down(v, off, 64);

    __shared__ float lds[4];
    int wid = t >> 6;
    if ((t & 63) == 0) lds[wid] = v;
    __syncthreads();
    if (t == 0)
        atomicAdd(out, lds[0] + lds[1] + lds[2] + lds[3]);
}

extern "C" void kernel_launch(void* const* d_in, const int* in_sizes, int n_in,
                              void* d_out, int out_size, void* d_ws, size_t ws_size,
                              hipStream_t stream) {
    const float* outputs = (const float*)d_in[0];  // (64,64,3)
    const float* c2ws    = (const float*)d_in[1];  // (64,4,4)
    const float* scales  = (const float*)d_in[2];  // (64,)
    const float* means   = (const float*)d_in[3];  // (100000,3)

    unsigned int* pmin = (unsigned int*)((char*)d_ws + WS_PMIN_OFF);
    float* out = (float*)d_out;

    // 0xFF bytes -> 0xFFFFFFFF = uint-max sentinel (beats any d2 bit pattern).
    hipMemsetAsync(pmin, 0xFF, NCOPY * P * sizeof(unsigned int), stream);
    hipMemsetAsync(out, 0, sizeof(float), stream);

    nn_kernel<<<dim3(G, QS), 256, 0, stream>>>(outputs, c2ws, scales, means, pmin);
    finish_kernel<<<P / 256, 256, 0, stream>>>(pmin, out);
}

// Round 4
// 100.497 us; speedup vs baseline: 1.2335x; 1.0348x over previous
//
#include <hip/hip_runtime.h>

#define MARGIN 0.0625f

// Problem sizes (fixed by the reference)
#define P 4096        // 64*64 query points
#define M 100000      // means
#define G 500         // mean-chunks: 500*200 = 100000 exactly
#define CHUNK 200     // means per block
#define NQUAD (CHUNK / 4)   // 50 float4 groups per LDS array
#define QS 4          // query slabs (grid = G*QS = 2000 blocks -> 8 blocks/CU)
#define R 4           // queries per thread (256*R*QS = 4096)
#define NCOPY 16      // atomic spread: pmin[NCOPY][P]

typedef float float2v __attribute__((ext_vector_type(2)));
typedef float float4v __attribute__((ext_vector_type(4)));

// ws layout (bytes):
//   pmin[NCOPY][P] (uint, float-bits running min) @ 0  -- 256 KB, L2-resident
//   Spread over 16 copies: the ~2M-atomic burst lands on 4096 cache lines
//   (~500 serialized ops/line) instead of 256 (~8K/line).
#define WS_PMIN_OFF 0

// ---------------------------------------------------------------------------
// Kernel 1 (fused): per-block mean transform -> LDS, query transform,
// 200-mean scan (software-pipelined LDS quads), filtered atomicMin into
// pmin[g & 15][p]. All stored d2 are fmax(...,0) >= +0.0 so uint order ==
// float order.
// ---------------------------------------------------------------------------
__global__ __launch_bounds__(256, 8) void nn_kernel(
    const float* __restrict__ outputs,   // [P*3]
    const float* __restrict__ c2ws,      // [64*16]
    const float* __restrict__ scales,    // [64]
    const float* __restrict__ means,     // [M*3] raw
    unsigned int* __restrict__ pmin)     // [NCOPY*P] float-bits, init 0xFF..
{
    const int t  = threadIdx.x;
    const int g  = blockIdx.x;
    const int qs = blockIdx.y;
    const int pbase = qs * (P / QS);
    const int mbase = g * CHUNK;

    // SoA chunk in LDS as float4 groups -> ds_read_b128, wave-uniform
    // addresses (broadcast, conflict-free).
    __shared__ float4v lxs[NQUAD], lys[NQUAD], lzs[NQUAD], lms[NQUAD];

    // ---- fused prep: transform this block's 200 raw means into LDS ----
    if (t < CHUNK) {
        const float* mp = means + 3 * (mbase + t);
        float x = mp[0], y = mp[1], z = mp[2];
        ((float*)lxs)[t] = -2.0f * x;
        ((float*)lys)[t] = -2.0f * y;
        ((float*)lzs)[t] = -2.0f * z;
        ((float*)lms)[t] = fmaf(x, x, fmaf(y, y, z * z));
    }

    // ---- queries: compute inline, splat to VGPR pairs once ----
    float2v qxs[R], qys[R], qzs[R], mn[R];
    float qq[R];
#pragma unroll
    for (int i = 0; i < R; ++i) {
        int p = pbase + i * 256 + t;
        int b = p >> 6;
        float s  = scales[b];
        float o0 = outputs[3 * p + 0];
        float o1 = outputs[3 * p + 1];
        float o2 = outputs[3 * p + 2];
        const float* cw = c2ws + b * 16;
        float q0 = fmaf(s, fmaf(cw[0],  o0, fmaf(cw[1],  o1, cw[2]  * o2)), cw[3]);
        float q1 = fmaf(s, fmaf(cw[4],  o0, fmaf(cw[5],  o1, cw[6]  * o2)), cw[7]);
        float q2 = fmaf(s, fmaf(cw[8],  o0, fmaf(cw[9],  o1, cw[10] * o2)), cw[11]);
        qq[i]  = fmaf(q0, q0, fmaf(q1, q1, q2 * q2));
        qxs[i] = (float2v){q0, q0};
        qys[i] = (float2v){q1, q1};
        qzs[i] = (float2v){q2, q2};
        mn[i]  = (float2v){1e30f, 1e30f};
    }

    __syncthreads();

    // ---- scan 50 mean-quads, software-pipelined: next quad's ds_reads
    // are issued before this quad's 32 packed FMAs, so LDS latency hides
    // under compute; 8 blocks/CU provide TLP for the rest.
    float4v cx = lxs[0], cy = lys[0], cz = lzs[0], cm = lms[0];
#pragma unroll 2
    for (int j = 0; j < NQUAD; ++j) {
        int jn = (j + 1 < NQUAD) ? j + 1 : 0;   // uniform, scalar select
        float4v nx = lxs[jn], ny = lys[jn], nz = lzs[jn], nm = lms[jn];

        float2v cx0 = __builtin_shufflevector(cx, cx, 0, 1);
        float2v cx1 = __builtin_shufflevector(cx, cx, 2, 3);
        float2v cy0 = __builtin_shufflevector(cy, cy, 0, 1);
        float2v cy1 = __builtin_shufflevector(cy, cy, 2, 3);
        float2v cz0 = __builtin_shufflevector(cz, cz, 0, 1);
        float2v cz1 = __builtin_shufflevector(cz, cz, 2, 3);
        float2v cm0 = __builtin_shufflevector(cm, cm, 0, 1);
        float2v cm1 = __builtin_shufflevector(cm, cm, 2, 3);
#pragma unroll
        for (int i = 0; i < R; ++i) {
            // d'(pair) = mm + (-2x)*qx + (-2y)*qy + (-2z)*qz
            float2v d0 = __builtin_elementwise_fma(qzs[i], cz0,
                         __builtin_elementwise_fma(qys[i], cy0,
                         __builtin_elementwise_fma(qxs[i], cx0, cm0)));
            float2v d1 = __builtin_elementwise_fma(qzs[i], cz1,
                         __builtin_elementwise_fma(qys[i], cy1,
                         __builtin_elementwise_fma(qxs[i], cx1, cm1)));
            mn[i] = __builtin_elementwise_min(mn[i], d0);
            mn[i] = __builtin_elementwise_min(mn[i], d1);
        }
        cx = nx; cy = ny; cz = nz; cm = nm;
    }

    // ---- epilogue: fold pair, add qq, clamp, filtered atomicMin into
    // this block's spread copy. Filter read may be stale (monotonically
    // decreasing target), so skipping is always safe; atomic is
    // authoritative.
    unsigned int* __restrict__ pm = pmin + (g & (NCOPY - 1)) * P;
#pragma unroll
    for (int i = 0; i < R; ++i) {
        int p = pbase + i * 256 + t;
        float m = fminf(mn[i][0], mn[i][1]);
        float d = fmaxf(qq[i] + m, 0.0f);
        unsigned int bits = __float_as_uint(d);
        if (bits < pm[p]) atomicMin(&pm[p], bits);
    }
}

// ---------------------------------------------------------------------------
// Kernel 2: loss. Fold the 16 spread copies (256 KB, L2-hot), then
// relu(MARGIN-d)/P, wave-reduce, one atomicAdd per block (16 blocks).
// ---------------------------------------------------------------------------
__global__ __launch_bounds__(256) void finish_kernel(
    const unsigned int* __restrict__ pmin,
    float* __restrict__ out)
{
    const int t = threadIdx.x;
    const int q = blockIdx.x * 256 + t;

    unsigned int mb = 0xFFFFFFFFu;
#pragma unroll
    for (int c = 0; c < NCOPY; ++c)
        mb = min(mb, pmin[c * P + q]);

    float m = __uint_as_float(mb);
    float v = fmaxf(MARGIN - m, 0.0f) * (1.0f / (float)P);

#pragma unroll
    for (int off = 32; off > 0; off >>= 1)
        v += __shfl_down(v, off, 64);

    __shared__ float lds[4];
    int wid = t >> 6;
    if ((t & 63) == 0) lds[wid] = v;
    __syncthreads();
    if (t == 0)
        atomicAdd(out, lds[0] + lds[1] + lds[2] + lds[3]);
}

extern "C" void kernel_launch(void* const* d_in, const int* in_sizes, int n_in,
                              void* d_out, int out_size, void* d_ws, size_t ws_size,
                              hipStream_t stream) {
    const float* outputs = (const float*)d_in[0];  // (64,64,3)
    const float* c2ws    = (const float*)d_in[1];  // (64,4,4)
    const float* scales  = (const float*)d_in[2];  // (64,)
    const float* means   = (const float*)d_in[3];  // (100000,3)

    unsigned int* pmin = (unsigned int*)((char*)d_ws + WS_PMIN_OFF);
    float* out = (float*)d_out;

    // 0xFF bytes -> 0xFFFFFFFF = uint-max sentinel (beats any d2 bit pattern).
    hipMemsetAsync(pmin, 0xFF, NCOPY * P * sizeof(unsigned int), stream);
    hipMemsetAsync(out, 0, sizeof(float), stream);

    nn_kernel<<<dim3(G, QS), 256, 0, stream>>>(outputs, c2ws, scales, means, pmin);
    finish_kernel<<<P / 256, 256, 0, stream>>>(pmin, out);
}